// Round 7
// baseline (305.518 us; speedup 1.0000x reference)
//
#include <hip/hip_runtime.h>
#include <hip/hip_bf16.h>
#include <stdint.h>

#define EMB    32
#define BATCH  128
#define NU     200000
#define KSEL   50000
#define XCOLS  33
#define SLOTS  64
#define NBLK1  256          // sweep1 grid (1 block/CU, 131KB LDS)
#define NBLK2  512          // sweep2 grid (2 blocks/CU, 67KB LDS)

// ws layout
#define OFF_SPRE   0
#define OFF_IIDE   16384
#define OFF_GHIST  32768    // 128*256 u32 = 131072; fallback sum_part overlay
#define OFF_BASE16 163840
#define OFF_PREFIX 164352
#define OFF_M2     164864
#define OFF_EQ     165376   // 128 counters, stride 16 u32 (64B)
#define OFF_CAND   173568   // fallback-path cand base
#define OFF_PART   173568   // partials: [256][128][256] u32 = 33.55 MB; later reused as sum_part
#define PART_BYTES ((size_t)NBLK1 * 128 * 256 * 4)

// quad (4-lane) xor-reduce: deterministic, bit-exact commutative pair sums
__device__ __forceinline__ float qsum(float x) {
    x += __int_as_float(__builtin_amdgcn_ds_swizzle(__float_as_int(x), 0x041F)); // lane ^= 1
    x += __int_as_float(__builtin_amdgcn_ds_swizzle(__float_as_int(x), 0x081F)); // lane ^= 2
    return x;
}
__device__ __forceinline__ float dot8(float4 a0, float4 a1, float4 b0, float4 b1) {
    return a0.x*b0.x + a0.y*b0.y + a0.z*b0.z + a0.w*b0.w
         + a1.x*b1.x + a1.y*b1.y + a1.z*b1.z + a1.w*b1.w;
}

// ---------------- prep ----------------
__global__ void prep_kernel(const float* __restrict__ x,
                            const float* __restrict__ iid_w,
                            const float* __restrict__ rp,
                            const float* __restrict__ uid,
                            float* __restrict__ s_pre,
                            float* __restrict__ iid_emb,
                            uint32_t* __restrict__ base16) {
    const int b = blockIdx.x;
    const int t = threadIdx.x;          // 64 threads
    __shared__ float xr[EMB];
    if (t < EMB) xr[t] = x[b * XCOLS + 1 + t];
    __syncthreads();
    if (t < EMB) {
        float acc = 0.f;
        #pragma unroll
        for (int k = 0; k < EMB; ++k) acc += xr[k] * rp[t * EMB + k];
        s_pre[b * EMB + t] = acc;
    } else {
        const int d = t - EMB;
        const int iid = (int)x[b * XCOLS];
        iid_emb[b * EMB + d] = iid_w[(size_t)iid * EMB + d];
    }
    __syncthreads();
    if (t == 0) {
        float dot = 0.f;
        #pragma unroll
        for (int k = 0; k < EMB; ++k) dot += s_pre[b * EMB + k] * uid[k];
        const uint32_t bits = __float_as_uint(fabsf(dot - 4.0f));
        const uint32_t hi = bits >> 16;
        base16[b] = (hi > 128u) ? (hi - 128u) : 0u;
    }
}

// ---------------- zero scratch ----------------
__global__ void zero_kernel(uint32_t* __restrict__ p, int n) {
    int i = blockIdx.x * blockDim.x + threadIdx.x;
    if (i < n) p[i] = 0u;
}

// ---------------- sweep1: quad k-split key histogram ----------------
template <bool PART>
__global__ __launch_bounds__(1024)
void sweep1_kernel(const float* __restrict__ s_pre,
                   const float* __restrict__ uid,
                   const uint32_t* __restrict__ base16,
                   uint32_t* __restrict__ gout,
                   int jchunk) {
    extern __shared__ uint32_t hist[];   // [128][257] padded
    const int t   = threadIdx.x;
    const int sub = t & 3;               // k-quarter within quad
    const int gid = t >> 2;              // 0..255
    const int b   = gid & 127;
    const int jl  = gid >> 7;            // 0..1 (wave-uniform)
    for (int i = t; i < 128 * 257; i += 1024) hist[i] = 0u;
    const float4* sp = (const float4*)(s_pre + b * EMB + sub * 8);
    const float4 sa = sp[0], sb = sp[1];
    const uint32_t base = base16[b];
    __syncthreads();

    const int j0 = blockIdx.x * jchunk;
    const int jend = min(j0 + jchunk, NU);
    int j = j0 + jl;
    for (; j + 2 < jend; j += 4) {
        const float4* r0 = (const float4*)(uid + (size_t)j * EMB + sub * 8);
        const float4* r1 = (const float4*)(uid + (size_t)(j + 2) * EMB + sub * 8);
        const float4 ua0 = r0[0], ub0 = r0[1];
        const float4 ua1 = r1[0], ub1 = r1[1];
        const float d0 = qsum(dot8(sa, sb, ua0, ub0));
        const float d1 = qsum(dot8(sa, sb, ua1, ub1));
        if (sub == 0) {
            const uint32_t bits0 = __float_as_uint(fabsf(d0 - 4.0f));
            const uint32_t bits1 = __float_as_uint(fabsf(d1 - 4.0f));
            int dg0 = (int)(bits0 >> 16) - (int)base; dg0 = dg0 < 0 ? 0 : (dg0 > 255 ? 255 : dg0);
            int dg1 = (int)(bits1 >> 16) - (int)base; dg1 = dg1 < 0 ? 0 : (dg1 > 255 ? 255 : dg1);
            atomicAdd(&hist[b * 257 + dg0], 1u);
            atomicAdd(&hist[b * 257 + dg1], 1u);
        }
    }
    for (; j < jend; j += 2) {
        const float4* r0 = (const float4*)(uid + (size_t)j * EMB + sub * 8);
        const float4 ua0 = r0[0], ub0 = r0[1];
        const float d0 = qsum(dot8(sa, sb, ua0, ub0));
        if (sub == 0) {
            const uint32_t bits0 = __float_as_uint(fabsf(d0 - 4.0f));
            int dg0 = (int)(bits0 >> 16) - (int)base; dg0 = dg0 < 0 ? 0 : (dg0 > 255 ? 255 : dg0);
            atomicAdd(&hist[b * 257 + dg0], 1u);
        }
    }
    __syncthreads();
    if (PART) {
        uint32_t* part = gout + (size_t)blockIdx.x * 32768;
        for (int i = t * 4; i < 32768; i += 4096) {
            const int row = i >> 8, d = i & 255;
            uint4 v;
            v.x = hist[row * 257 + d + 0];
            v.y = hist[row * 257 + d + 1];
            v.z = hist[row * 257 + d + 2];
            v.w = hist[row * 257 + d + 3];
            *(uint4*)(part + i) = v;
        }
    } else {
        for (int i = t; i < 128 * 256; i += 1024) {
            const uint32_t c = hist[(i >> 8) * 257 + (i & 255)];
            if (c) atomicAdd(&gout[i], c);
        }
    }
}

// ---------------- scan1 (atomic-ghist fallback) ----------------
__global__ void scan1_kernel(const uint32_t* __restrict__ ghist,
                             const uint32_t* __restrict__ base16,
                             uint32_t* __restrict__ prefix16,
                             uint32_t* __restrict__ m2) {
    const int b = threadIdx.x;           // 128 threads, 1 block
    uint32_t cum = 0, before = 0;
    int c1 = 255;
    for (int d = 0; d < 256; ++d) {
        const uint32_t c = ghist[b * 256 + d];
        if (cum + c >= (uint32_t)KSEL) { c1 = d; before = cum; break; }
        cum += c;
        if (d == 255) before = cum;
    }
    prefix16[b] = base16[b] + (uint32_t)c1;
    m2[b] = (uint32_t)KSEL - before;
}

// ---------------- scan1 (partials path) ----------------
__global__ __launch_bounds__(256)
void scan1_part_kernel(const uint32_t* __restrict__ part,
                       const uint32_t* __restrict__ base16,
                       uint32_t* __restrict__ prefix16,
                       uint32_t* __restrict__ m2) {
    const int row = blockIdx.x;          // 128 blocks
    const int t = threadIdx.x;           // 256 threads = digits
    __shared__ uint32_t h[256];
    uint32_t a0 = 0, a1 = 0, a2 = 0, a3 = 0;
    const uint32_t* p = part + (size_t)row * 256 + t;
    for (int g = 0; g < NBLK1; g += 4) {
        a0 += p[(size_t)(g + 0) * 32768];
        a1 += p[(size_t)(g + 1) * 32768];
        a2 += p[(size_t)(g + 2) * 32768];
        a3 += p[(size_t)(g + 3) * 32768];
    }
    h[t] = a0 + a1 + a2 + a3;
    __syncthreads();
    if (t == 0) {
        uint32_t cum = 0, before = 0; int c1 = 255;
        for (int d = 0; d < 256; ++d) {
            const uint32_t c = h[d];
            if (cum + c >= (uint32_t)KSEL) { c1 = d; before = cum; break; }
            cum += c;
            if (d == 255) before = cum;
        }
        prefix16[row] = base16[row] + (uint32_t)c1;
        m2[row] = (uint32_t)KSEL - before;
    }
}

// ---------------- sweep2: quad k-split dual-dot; below-sum + candidates ----------
__global__ __launch_bounds__(1024)
void sweep2_kernel(const float* __restrict__ s_pre,
                   const float* __restrict__ iid_emb,
                   const float* __restrict__ uid,
                   const uint32_t* __restrict__ prefix16,
                   uint32_t* __restrict__ eq_cnt,
                   float* __restrict__ sum_part,
                   uint64_t* __restrict__ cand,
                   int cap, int jchunk) {
    extern __shared__ char smem2[];
    uint64_t* lcand  = (uint64_t*)smem2;                   // 65536
    uint32_t* lcnt   = (uint32_t*)(smem2 + 65536);         // 512
    uint32_t* lbase  = (uint32_t*)(smem2 + 66048);         // 512
    float*    sums_b = (float*)(smem2 + 66560);            // 512
    const int t   = threadIdx.x;
    const int sub = t & 3;
    const int gid = t >> 2;              // 0..255
    const int b   = gid & 127;
    const int jl  = gid >> 7;            // 0..1
    if (t < 128) { lcnt[t] = 0u; sums_b[t] = 0.f; }
    const float4* sp = (const float4*)(s_pre + b * EMB + sub * 8);
    const float4 sa = sp[0], sb = sp[1];
    const float4* ep = (const float4*)(iid_emb + b * EMB + sub * 8);
    const float4 ea = ep[0], eb = ep[1];
    const uint32_t pfx = prefix16[b];
    __syncthreads();

    const int j0 = blockIdx.x * jchunk;
    const int jend = min(j0 + jchunk, NU);
    float local = 0.f;
    int j = j0 + jl;
    for (; j + 2 < jend; j += 4) {
        const float4* r0 = (const float4*)(uid + (size_t)j * EMB + sub * 8);
        const float4* r1 = (const float4*)(uid + (size_t)(j + 2) * EMB + sub * 8);
        const float4 ua0 = r0[0], ub0 = r0[1];
        const float4 ua1 = r1[0], ub1 = r1[1];
        const float d0 = qsum(dot8(sa, sb, ua0, ub0));
        const float v0 = qsum(dot8(ea, eb, ua0, ub0));
        const float d1 = qsum(dot8(sa, sb, ua1, ub1));
        const float v1 = qsum(dot8(ea, eb, ua1, ub1));
        if (sub == 0) {
            const uint32_t bits0 = __float_as_uint(fabsf(d0 - 4.0f));
            const uint32_t bits1 = __float_as_uint(fabsf(d1 - 4.0f));
            const uint32_t hi0 = bits0 >> 16, hi1 = bits1 >> 16;
            local += (hi0 < pfx) ? v0 : 0.f;
            local += (hi1 < pfx) ? v1 : 0.f;
            if (hi0 == pfx) {
                const uint32_t pos = atomicAdd(&lcnt[b], 1u);
                const uint64_t pk = ((uint64_t)bits0 << 32) | (uint32_t)j;
                if (pos < (uint32_t)SLOTS) lcand[b * SLOTS + pos] = pk;
                else {
                    const uint32_t g = atomicAdd(&eq_cnt[b * 16], 1u);
                    if (g < (uint32_t)cap) cand[(size_t)b * cap + g] = pk;
                }
            }
            if (hi1 == pfx) {
                const uint32_t pos = atomicAdd(&lcnt[b], 1u);
                const uint64_t pk = ((uint64_t)bits1 << 32) | (uint32_t)(j + 2);
                if (pos < (uint32_t)SLOTS) lcand[b * SLOTS + pos] = pk;
                else {
                    const uint32_t g = atomicAdd(&eq_cnt[b * 16], 1u);
                    if (g < (uint32_t)cap) cand[(size_t)b * cap + g] = pk;
                }
            }
        }
    }
    for (; j < jend; j += 2) {
        const float4* r0 = (const float4*)(uid + (size_t)j * EMB + sub * 8);
        const float4 ua0 = r0[0], ub0 = r0[1];
        const float d0 = qsum(dot8(sa, sb, ua0, ub0));
        const float v0 = qsum(dot8(ea, eb, ua0, ub0));
        if (sub == 0) {
            const uint32_t bits0 = __float_as_uint(fabsf(d0 - 4.0f));
            const uint32_t hi0 = bits0 >> 16;
            local += (hi0 < pfx) ? v0 : 0.f;
            if (hi0 == pfx) {
                const uint32_t pos = atomicAdd(&lcnt[b], 1u);
                const uint64_t pk = ((uint64_t)bits0 << 32) | (uint32_t)j;
                if (pos < (uint32_t)SLOTS) lcand[b * SLOTS + pos] = pk;
                else {
                    const uint32_t g = atomicAdd(&eq_cnt[b * 16], 1u);
                    if (g < (uint32_t)cap) cand[(size_t)b * cap + g] = pk;
                }
            }
        }
    }
    // two leader contributions per b (jl=0,1): float add is commutative bit-exact
    if (sub == 0 && local != 0.f) atomicAdd(&sums_b[b], local);
    __syncthreads();
    if (t < 128) {
        sum_part[(size_t)blockIdx.x * 128 + t] = sums_b[t];
        const uint32_t n = min(lcnt[t], (uint32_t)SLOTS);
        lbase[t] = atomicAdd(&eq_cnt[t * 16], n);
    }
    __syncthreads();
    for (int i = t; i < 128 * SLOTS; i += 1024) {
        const int bb = i >> 6;             // SLOTS == 64
        const int sl = i & 63;
        if (sl < (int)min(lcnt[bb], (uint32_t)SLOTS)) {
            const uint32_t p = lbase[bb] + (uint32_t)sl;
            if (p < (uint32_t)cap) cand[(size_t)bb * cap + p] = lcand[i];
        }
    }
}

// ---------------- finalize ----------------
__global__ __launch_bounds__(256)
void final_kernel(const float* __restrict__ iid_emb,
                  const float* __restrict__ uid,
                  const uint32_t* __restrict__ m2_,
                  const uint32_t* __restrict__ eq_cnt,
                  const float* __restrict__ sum_part,
                  const uint64_t* __restrict__ cand,
                  int cap, int g2, float* __restrict__ out) {
    const int b = blockIdx.x;
    const int t = threadIdx.x;           // 256 threads
    __shared__ float red[256];
    __shared__ uint32_t hist[256];
    __shared__ float e[EMB];
    __shared__ uint32_t tie[128];
    __shared__ uint32_t tiecnt, sc2, sm3, sc3, sm4;
    __shared__ float sbelow;
    if (t < EMB) e[t] = iid_emb[b * EMB + t];
    if (t == 0) tiecnt = 0u;
    hist[t] = 0u;
    {
        float acc = 0.f;
        for (int g = t; g < g2; g += 256) acc += sum_part[(size_t)g * 128 + b];
        red[t] = acc;
    }
    __syncthreads();
    for (int s = 128; s > 0; s >>= 1) { if (t < s) red[t] += red[t + s]; __syncthreads(); }
    if (t == 0) sbelow = red[0];
    __syncthreads();

    const uint32_t ec = eq_cnt[b * 16];
    const int cnt = (int)(ec < (uint32_t)cap ? ec : (uint32_t)cap);
    const uint64_t* cb = cand + (size_t)b * cap;

    for (int i = t; i < cnt; i += 256) {
        const uint32_t low16 = (uint32_t)(cb[i] >> 32) & 0xFFFFu;
        atomicAdd(&hist[low16 >> 8], 1u);
    }
    __syncthreads();
    if (t == 0) {
        const uint32_t m2v = m2_[b];
        uint32_t cum = 0, before = 0; int c2 = 255;
        for (int d = 0; d < 256; ++d) {
            const uint32_t c = hist[d];
            if (cum + c >= m2v) { c2 = d; before = cum; break; }
            cum += c;
        }
        sc2 = (uint32_t)c2; sm3 = m2v - before;
    }
    __syncthreads();
    const uint32_t c2 = sc2;
    hist[t] = 0u;
    __syncthreads();

    for (int i = t; i < cnt; i += 256) {
        const uint32_t low16 = (uint32_t)(cb[i] >> 32) & 0xFFFFu;
        if ((low16 >> 8) == c2) atomicAdd(&hist[low16 & 255u], 1u);
    }
    __syncthreads();
    if (t == 0) {
        const uint32_t m3 = sm3;
        uint32_t cum = 0, before = 0; int c3 = 255;
        for (int d = 0; d < 256; ++d) {
            const uint32_t c = hist[d];
            if (cum + c >= m3) { c3 = d; before = cum; break; }
            cum += c;
        }
        sc3 = (uint32_t)c3; sm4 = m3 - before;
    }
    __syncthreads();
    const uint32_t T16 = (c2 << 8) | sc3;

    float local = 0.f;
    for (int i = t; i < cnt; i += 256) {
        const uint64_t cv = cb[i];
        const uint32_t low16 = (uint32_t)(cv >> 32) & 0xFFFFu;
        if (low16 < T16) {
            const uint32_t j = (uint32_t)cv;
            const float4* u4 = (const float4*)(uid + (size_t)j * EMB);
            float dv = 0.f;
            #pragma unroll
            for (int q = 0; q < 8; ++q) {
                float4 u = u4[q];
                dv += e[4*q+0]*u.x + e[4*q+1]*u.y + e[4*q+2]*u.z + e[4*q+3]*u.w;
            }
            local += dv;
        } else if (low16 == T16) {
            const uint32_t pos = atomicAdd(&tiecnt, 1u);
            if (pos < 128u) tie[pos] = (uint32_t)cv;
        }
    }
    red[t] = local;
    __syncthreads();
    for (int s = 128; s > 0; s >>= 1) { if (t < s) red[t] += red[t + s]; __syncthreads(); }
    if (t == 0) {
        int tc = (int)(tiecnt < 128u ? tiecnt : 128u);
        for (int i = 1; i < tc; ++i) {
            const uint32_t v = tie[i]; int k = i - 1;
            while (k >= 0 && tie[k] > v) { tie[k+1] = tie[k]; --k; }
            tie[k+1] = v;
        }
        const int m4 = (int)sm4;
        float tsum = 0.f;
        for (int i = 0; i < m4 && i < tc; ++i) {
            const uint32_t j = tie[i];
            float dv = 0.f;
            for (int d = 0; d < EMB; ++d) dv += e[d] * uid[(size_t)j * EMB + d];
            tsum += dv;
        }
        out[b] = (sbelow + red[0] + tsum) / (float)KSEL;
    }
}

extern "C" void kernel_launch(void* const* d_in, const int* in_sizes, int n_in,
                              void* d_out, int out_size, void* d_ws, size_t ws_size,
                              hipStream_t stream) {
    const float* x     = (const float*)d_in[0];
    const float* uid   = (const float*)d_in[1];
    const float* iid_w = (const float*)d_in[2];
    const float* rp    = (const float*)d_in[3];
    float* out = (float*)d_out;

    char* ws = (char*)d_ws;
    float*    s_pre    = (float*)(ws + OFF_SPRE);
    float*    iid_emb  = (float*)(ws + OFF_IIDE);
    uint32_t* ghist    = (uint32_t*)(ws + OFF_GHIST);
    uint32_t* base16   = (uint32_t*)(ws + OFF_BASE16);
    uint32_t* prefix16 = (uint32_t*)(ws + OFF_PREFIX);
    uint32_t* m2       = (uint32_t*)(ws + OFF_M2);
    uint32_t* eq_cnt   = (uint32_t*)(ws + OFF_EQ);
    uint32_t* part     = (uint32_t*)(ws + OFF_PART);

    const size_t off_cand2 = OFF_PART + PART_BYTES;
    const bool use_part = ws_size >= off_cand2 + (size_t)128 * 8 * 4096;

    uint64_t* cand;
    int cap;
    float* sum_part;
    int G2, JC2;
    if (use_part) {
        cand = (uint64_t*)(ws + off_cand2);
        long long cap_ll = ((long long)ws_size - (long long)off_cand2) / (128LL * 8LL);
        cap = (int)(cap_ll > 16384 ? 16384 : cap_ll);
        sum_part = (float*)part;       // part is dead after scan1_part; reuse as [512][128]
        G2 = NBLK2;
    } else {
        cand = (uint64_t*)(ws + OFF_CAND);
        long long cap_ll = ((long long)ws_size - OFF_CAND) / (128LL * 8LL);
        cap = (int)(cap_ll > 16384 ? 16384 : (cap_ll < 1 ? 1 : cap_ll));
        sum_part = (float*)(ws + OFF_GHIST);   // [256][128] overlay after scan1
        G2 = NBLK1;
    }
    JC2 = (NU + G2 - 1) / G2;

    {
        const int n = (OFF_CAND - OFF_GHIST) / 4;      // ghist + base16/prefix/m2 + eq_cnt
        zero_kernel<<<(n + 255) / 256, 256, 0, stream>>>((uint32_t*)(ws + OFF_GHIST), n);
    }
    prep_kernel<<<BATCH, 64, 0, stream>>>(x, iid_w, rp, uid, s_pre, iid_emb, base16);

    const int JC1 = (NU + NBLK1 - 1) / NBLK1;          // 782
    if (use_part) {
        sweep1_kernel<true><<<NBLK1, 1024, 128 * 257 * 4, stream>>>(s_pre, uid, base16, part, JC1);
        scan1_part_kernel<<<BATCH, 256, 0, stream>>>(part, base16, prefix16, m2);
    } else {
        sweep1_kernel<false><<<NBLK1, 1024, 128 * 257 * 4, stream>>>(s_pre, uid, base16, ghist, JC1);
        scan1_kernel<<<1, 128, 0, stream>>>(ghist, base16, prefix16, m2);
    }

    sweep2_kernel<<<G2, 1024, 65536 + 512 + 512 + 512, stream>>>(s_pre, iid_emb, uid,
                                                                 prefix16, eq_cnt, sum_part,
                                                                 cand, cap, JC2);

    final_kernel<<<BATCH, 256, 0, stream>>>(iid_emb, uid, m2, eq_cnt, sum_part,
                                            cand, cap, G2, out);
}

// Round 8
// 248.408 us; speedup vs baseline: 1.2299x; 1.2299x over previous
//
#include <hip/hip_runtime.h>
#include <hip/hip_bf16.h>
#include <stdint.h>

#define EMB    32
#define BATCH  128
#define NU     200000
#define KSEL   50000
#define XCOLS  33
#define SLOTS  64
#define G1     512          // sweep1 grid (2 blocks/CU, 66KB LDS)
#define G2P    512          // sweep2 grid, part path
#define G2F    256          // sweep2 grid, fallback path
#define HISTW  (128 * 129)  // packed u16 hist words per block

// ws layout
#define OFF_SPRE   0
#define OFF_IIDE   16384
#define OFF_GHIST  32768    // fallback: 128*256 u32 ghist; also fallback sum_part overlay
#define OFF_BASE16 163840
#define OFF_PREFIX 164352
#define OFF_M2     164864
#define OFF_EQ     165376   // 128 counters, stride 16 u32
#define OFF_CAND   173568   // fallback cand base
#define OFF_PART   173568   // part path: [512][16512] u32 = 33.82 MB; reused as sum_part after scan
#define PART_BYTES ((size_t)G1 * HISTW * 4)

// lane^1 exchange via DPP quad_perm [1,0,3,2] — VALU pipe, no LDS
__device__ __forceinline__ float xor1(float x) {
    int r = __builtin_amdgcn_update_dpp(0, __float_as_int(x), 0xB1, 0xF, 0xF, true);
    return __int_as_float(r);
}

// ---------------- prep ----------------
__global__ void prep_kernel(const float* __restrict__ x,
                            const float* __restrict__ iid_w,
                            const float* __restrict__ rp,
                            const float* __restrict__ uid,
                            float* __restrict__ s_pre,
                            float* __restrict__ iid_emb,
                            uint32_t* __restrict__ base16,
                            uint32_t* __restrict__ eq_cnt) {
    const int b = blockIdx.x;
    const int t = threadIdx.x;          // 64 threads
    __shared__ float xr[EMB];
    if (t < EMB) xr[t] = x[b * XCOLS + 1 + t];
    if (t == 63) eq_cnt[b * 16] = 0u;
    __syncthreads();
    if (t < EMB) {
        float acc = 0.f;
        #pragma unroll
        for (int k = 0; k < EMB; ++k) acc += xr[k] * rp[t * EMB + k];
        s_pre[b * EMB + t] = acc;
    } else {
        const int d = t - EMB;
        const int iid = (int)x[b * XCOLS];
        iid_emb[b * EMB + d] = iid_w[(size_t)iid * EMB + d];
    }
    __syncthreads();
    if (t == 0) {
        float dot = 0.f;
        #pragma unroll
        for (int k = 0; k < EMB; ++k) dot += s_pre[b * EMB + k] * uid[k];
        const uint32_t bits = __float_as_uint(fabsf(dot - 4.0f));
        const uint32_t hi = bits >> 16;
        base16[b] = (hi > 128u) ? (hi - 128u) : 0u;
    }
}

// ---------------- zero scratch (fallback path only) ----------------
__global__ void zero_kernel(uint32_t* __restrict__ p, int n) {
    int i = blockIdx.x * blockDim.x + threadIdx.x;
    if (i < n) p[i] = 0u;
}

// ---------------- sweep1: per-lane key dot, packed-u16 LDS hist ----------------
template <bool PART>
__global__ __launch_bounds__(1024)
void sweep1_kernel(const float* __restrict__ s_pre,
                   const float* __restrict__ uid,
                   const uint32_t* __restrict__ base16,
                   uint32_t* __restrict__ gout,
                   int jchunk) {
    extern __shared__ uint32_t hist[];   // [128][129] packed u16 pairs = 66048 B
    const int t  = threadIdx.x;
    const int b  = t & 127;
    const int jl = t >> 7;               // 0..7, wave-uniform
    for (int i = t; i < HISTW; i += 1024) hist[i] = 0u;
    float s[EMB];
    #pragma unroll
    for (int d = 0; d < EMB; ++d) s[d] = s_pre[b * EMB + d];
    const uint32_t base = base16[b];
    __syncthreads();

    const int j0 = blockIdx.x * jchunk;
    const int jend = min(j0 + jchunk, NU);
    int j = j0 + jl;
    for (; j + 8 < jend; j += 16) {
        const int ju = __builtin_amdgcn_readfirstlane(j);
        const float* up0 = uid + (size_t)ju * EMB;
        const float* up1 = up0 + 8 * EMB;
        float d0 = 0.f, d1 = 0.f;
        #pragma unroll
        for (int k = 0; k < EMB; ++k) {
            d0 += s[k] * up0[k];
            d1 += s[k] * up1[k];
        }
        const uint32_t bits0 = __float_as_uint(fabsf(d0 - 4.0f));
        const uint32_t bits1 = __float_as_uint(fabsf(d1 - 4.0f));
        int dg0 = (int)(bits0 >> 16) - (int)base; dg0 = dg0 < 0 ? 0 : (dg0 > 255 ? 255 : dg0);
        int dg1 = (int)(bits1 >> 16) - (int)base; dg1 = dg1 < 0 ? 0 : (dg1 > 255 ? 255 : dg1);
        atomicAdd(&hist[b * 129 + (dg0 >> 1)], 1u << ((dg0 & 1) * 16));
        atomicAdd(&hist[b * 129 + (dg1 >> 1)], 1u << ((dg1 & 1) * 16));
    }
    for (; j < jend; j += 8) {
        const int ju = __builtin_amdgcn_readfirstlane(j);
        const float* up0 = uid + (size_t)ju * EMB;
        float d0 = 0.f;
        #pragma unroll
        for (int k = 0; k < EMB; ++k) d0 += s[k] * up0[k];
        const uint32_t bits0 = __float_as_uint(fabsf(d0 - 4.0f));
        int dg0 = (int)(bits0 >> 16) - (int)base; dg0 = dg0 < 0 ? 0 : (dg0 > 255 ? 255 : dg0);
        atomicAdd(&hist[b * 129 + (dg0 >> 1)], 1u << ((dg0 & 1) * 16));
    }
    __syncthreads();
    if (PART) {
        uint32_t* part = gout + (size_t)blockIdx.x * HISTW;
        for (int i = t; i < HISTW; i += 1024) part[i] = hist[i];
    } else {
        for (int i = t; i < 128 * 256; i += 1024) {
            const int r = i >> 8, d = i & 255;
            const uint32_t c = (hist[r * 129 + (d >> 1)] >> ((d & 1) * 16)) & 0xFFFFu;
            if (c) atomicAdd(&gout[i], c);
        }
    }
}

// ---------------- scan1 (fallback) ----------------
__global__ void scan1_kernel(const uint32_t* __restrict__ ghist,
                             const uint32_t* __restrict__ base16,
                             uint32_t* __restrict__ prefix16,
                             uint32_t* __restrict__ m2) {
    const int b = threadIdx.x;           // 128 threads, 1 block
    uint32_t cum = 0, before = 0;
    int c1 = 255;
    for (int d = 0; d < 256; ++d) {
        const uint32_t c = ghist[b * 256 + d];
        if (cum + c >= (uint32_t)KSEL) { c1 = d; before = cum; break; }
        cum += c;
        if (d == 255) before = cum;
    }
    prefix16[b] = base16[b] + (uint32_t)c1;
    m2[b] = (uint32_t)KSEL - before;
}

// ---------------- scan1 (part path): merge packed block hists ----------
__global__ __launch_bounds__(256)
void scan1_part_kernel(const uint32_t* __restrict__ part,
                       const uint32_t* __restrict__ base16,
                       uint32_t* __restrict__ prefix16,
                       uint32_t* __restrict__ m2) {
    const int row = blockIdx.x;          // 128 blocks
    const int t = threadIdx.x;           // 256 threads = digits
    __shared__ uint32_t h[256];
    const int sh = (t & 1) * 16;
    const uint32_t* p = part + (size_t)row * 129 + (t >> 1);
    uint32_t a0 = 0, a1 = 0, a2 = 0, a3 = 0;
    for (int g = 0; g < G1; g += 4) {
        a0 += (p[(size_t)(g + 0) * HISTW] >> sh) & 0xFFFFu;
        a1 += (p[(size_t)(g + 1) * HISTW] >> sh) & 0xFFFFu;
        a2 += (p[(size_t)(g + 2) * HISTW] >> sh) & 0xFFFFu;
        a3 += (p[(size_t)(g + 3) * HISTW] >> sh) & 0xFFFFu;
    }
    h[t] = a0 + a1 + a2 + a3;
    __syncthreads();
    if (t == 0) {
        uint32_t cum = 0, before = 0; int c1 = 255;
        for (int d = 0; d < 256; ++d) {
            const uint32_t c = h[d];
            if (cum + c >= (uint32_t)KSEL) { c1 = d; before = cum; break; }
            cum += c;
            if (d == 255) before = cum;
        }
        prefix16[row] = base16[row] + (uint32_t)c1;
        m2[row] = (uint32_t)KSEL - before;
    }
}

// ---------------- sweep2: lane-pair role split (even=key, odd=val), DPP exchange ----
__global__ __launch_bounds__(1024)
void sweep2_kernel(const float* __restrict__ s_pre,
                   const float* __restrict__ iid_emb,
                   const float* __restrict__ uid,
                   const uint32_t* __restrict__ prefix16,
                   uint32_t* __restrict__ eq_cnt,
                   float* __restrict__ sum_part,
                   uint64_t* __restrict__ cand,
                   int cap, int jchunk) {
    extern __shared__ char smem2[];
    uint64_t* lcand  = (uint64_t*)smem2;                   // 65536
    uint32_t* lcnt   = (uint32_t*)(smem2 + 65536);         // 512
    uint32_t* lbase  = (uint32_t*)(smem2 + 66048);         // 512
    float*    sums_b = (float*)(smem2 + 66560);            // 512
    const int t   = threadIdx.x;
    const int par = t & 1;               // 0: key (s_pre), 1: val (iid_emb)
    const int pr  = t >> 1;              // 0..511
    const int b   = pr & 127;
    const int jl  = pr >> 7;             // 0..3, wave-uniform
    if (t < 128) { lcnt[t] = 0u; sums_b[t] = 0.f; }
    float c[EMB];
    {
        const float4* cp4 = (const float4*)((par ? iid_emb : s_pre) + b * EMB);
        #pragma unroll
        for (int q = 0; q < 8; ++q) {
            float4 v = cp4[q];
            c[4*q+0] = v.x; c[4*q+1] = v.y; c[4*q+2] = v.z; c[4*q+3] = v.w;
        }
    }
    const uint32_t pfx = prefix16[b];
    __syncthreads();

    const int j0 = blockIdx.x * jchunk;
    const int jend = min(j0 + jchunk, NU);
    float local = 0.f;
    int j = j0 + jl;
    for (; j + 4 < jend; j += 8) {
        const int ju = __builtin_amdgcn_readfirstlane(j);
        const float* up0 = uid + (size_t)ju * EMB;
        const float* up1 = up0 + 4 * EMB;
        float a0 = 0.f, a1 = 0.f;
        #pragma unroll
        for (int k = 0; k < EMB; ++k) {
            a0 += c[k] * up0[k];
            a1 += c[k] * up1[k];
        }
        const float p0 = xor1(a0);       // even lane receives partner's val-dot
        const float p1 = xor1(a1);
        if (par == 0) {
            const uint32_t bits0 = __float_as_uint(fabsf(a0 - 4.0f));
            const uint32_t bits1 = __float_as_uint(fabsf(a1 - 4.0f));
            const uint32_t hi0 = bits0 >> 16, hi1 = bits1 >> 16;
            local += (hi0 < pfx) ? p0 : 0.f;
            local += (hi1 < pfx) ? p1 : 0.f;
            if (hi0 == pfx) {
                const uint32_t pos = atomicAdd(&lcnt[b], 1u);
                const uint64_t pk = ((uint64_t)bits0 << 32) | (uint32_t)j;
                if (pos < (uint32_t)SLOTS) lcand[b * SLOTS + pos] = pk;
                else {
                    const uint32_t g = atomicAdd(&eq_cnt[b * 16], 1u);
                    if (g < (uint32_t)cap) cand[(size_t)b * cap + g] = pk;
                }
            }
            if (hi1 == pfx) {
                const uint32_t pos = atomicAdd(&lcnt[b], 1u);
                const uint64_t pk = ((uint64_t)bits1 << 32) | (uint32_t)(j + 4);
                if (pos < (uint32_t)SLOTS) lcand[b * SLOTS + pos] = pk;
                else {
                    const uint32_t g = atomicAdd(&eq_cnt[b * 16], 1u);
                    if (g < (uint32_t)cap) cand[(size_t)b * cap + g] = pk;
                }
            }
        }
    }
    for (; j < jend; j += 4) {
        const int ju = __builtin_amdgcn_readfirstlane(j);
        const float* up0 = uid + (size_t)ju * EMB;
        float a0 = 0.f;
        #pragma unroll
        for (int k = 0; k < EMB; ++k) a0 += c[k] * up0[k];
        const float p0 = xor1(a0);
        if (par == 0) {
            const uint32_t bits0 = __float_as_uint(fabsf(a0 - 4.0f));
            const uint32_t hi0 = bits0 >> 16;
            local += (hi0 < pfx) ? p0 : 0.f;
            if (hi0 == pfx) {
                const uint32_t pos = atomicAdd(&lcnt[b], 1u);
                const uint64_t pk = ((uint64_t)bits0 << 32) | (uint32_t)j;
                if (pos < (uint32_t)SLOTS) lcand[b * SLOTS + pos] = pk;
                else {
                    const uint32_t g = atomicAdd(&eq_cnt[b * 16], 1u);
                    if (g < (uint32_t)cap) cand[(size_t)b * cap + g] = pk;
                }
            }
        }
    }
    if (par == 0 && local != 0.f) atomicAdd(&sums_b[b], local);
    __syncthreads();
    if (t < 128) {
        sum_part[(size_t)blockIdx.x * 128 + t] = sums_b[t];
        const uint32_t n = min(lcnt[t], (uint32_t)SLOTS);
        lbase[t] = atomicAdd(&eq_cnt[t * 16], n);
    }
    __syncthreads();
    for (int i = t; i < 128 * SLOTS; i += 1024) {
        const int bb = i >> 6;             // SLOTS == 64
        const int sl = i & 63;
        if (sl < (int)min(lcnt[bb], (uint32_t)SLOTS)) {
            const uint32_t p = lbase[bb] + (uint32_t)sl;
            if (p < (uint32_t)cap) cand[(size_t)bb * cap + p] = lcand[i];
        }
    }
}

// ---------------- finalize ----------------
__global__ __launch_bounds__(256)
void final_kernel(const float* __restrict__ iid_emb,
                  const float* __restrict__ uid,
                  const uint32_t* __restrict__ m2_,
                  const uint32_t* __restrict__ eq_cnt,
                  const float* __restrict__ sum_part,
                  const uint64_t* __restrict__ cand,
                  int cap, int g2, float* __restrict__ out) {
    const int b = blockIdx.x;
    const int t = threadIdx.x;           // 256 threads
    __shared__ float red[256];
    __shared__ uint32_t hist[256];
    __shared__ float e[EMB];
    __shared__ uint32_t tie[128];
    __shared__ uint32_t tiecnt, sc2, sm3, sc3, sm4;
    __shared__ float sbelow;
    if (t < EMB) e[t] = iid_emb[b * EMB + t];
    if (t == 0) tiecnt = 0u;
    hist[t] = 0u;
    {
        float acc = 0.f;
        for (int g = t; g < g2; g += 256) acc += sum_part[(size_t)g * 128 + b];
        red[t] = acc;
    }
    __syncthreads();
    for (int s = 128; s > 0; s >>= 1) { if (t < s) red[t] += red[t + s]; __syncthreads(); }
    if (t == 0) sbelow = red[0];
    __syncthreads();

    const uint32_t ec = eq_cnt[b * 16];
    const int cnt = (int)(ec < (uint32_t)cap ? ec : (uint32_t)cap);
    const uint64_t* cb = cand + (size_t)b * cap;

    for (int i = t; i < cnt; i += 256) {
        const uint32_t low16 = (uint32_t)(cb[i] >> 32) & 0xFFFFu;
        atomicAdd(&hist[low16 >> 8], 1u);
    }
    __syncthreads();
    if (t == 0) {
        const uint32_t m2v = m2_[b];
        uint32_t cum = 0, before = 0; int c2 = 255;
        for (int d = 0; d < 256; ++d) {
            const uint32_t c = hist[d];
            if (cum + c >= m2v) { c2 = d; before = cum; break; }
            cum += c;
        }
        sc2 = (uint32_t)c2; sm3 = m2v - before;
    }
    __syncthreads();
    const uint32_t c2 = sc2;
    hist[t] = 0u;
    __syncthreads();

    for (int i = t; i < cnt; i += 256) {
        const uint32_t low16 = (uint32_t)(cb[i] >> 32) & 0xFFFFu;
        if ((low16 >> 8) == c2) atomicAdd(&hist[low16 & 255u], 1u);
    }
    __syncthreads();
    if (t == 0) {
        const uint32_t m3 = sm3;
        uint32_t cum = 0, before = 0; int c3 = 255;
        for (int d = 0; d < 256; ++d) {
            const uint32_t c = hist[d];
            if (cum + c >= m3) { c3 = d; before = cum; break; }
            cum += c;
        }
        sc3 = (uint32_t)c3; sm4 = m3 - before;
    }
    __syncthreads();
    const uint32_t T16 = (c2 << 8) | sc3;

    float local = 0.f;
    for (int i = t; i < cnt; i += 256) {
        const uint64_t cv = cb[i];
        const uint32_t low16 = (uint32_t)(cv >> 32) & 0xFFFFu;
        if (low16 < T16) {
            const uint32_t j = (uint32_t)cv;
            const float4* u4 = (const float4*)(uid + (size_t)j * EMB);
            float dv = 0.f;
            #pragma unroll
            for (int q = 0; q < 8; ++q) {
                float4 u = u4[q];
                dv += e[4*q+0]*u.x + e[4*q+1]*u.y + e[4*q+2]*u.z + e[4*q+3]*u.w;
            }
            local += dv;
        } else if (low16 == T16) {
            const uint32_t pos = atomicAdd(&tiecnt, 1u);
            if (pos < 128u) tie[pos] = (uint32_t)cv;
        }
    }
    red[t] = local;
    __syncthreads();
    for (int s = 128; s > 0; s >>= 1) { if (t < s) red[t] += red[t + s]; __syncthreads(); }
    if (t == 0) {
        int tc = (int)(tiecnt < 128u ? tiecnt : 128u);
        for (int i = 1; i < tc; ++i) {
            const uint32_t v = tie[i]; int k = i - 1;
            while (k >= 0 && tie[k] > v) { tie[k+1] = tie[k]; --k; }
            tie[k+1] = v;
        }
        const int m4 = (int)sm4;
        float tsum = 0.f;
        for (int i = 0; i < m4 && i < tc; ++i) {
            const uint32_t j = tie[i];
            float dv = 0.f;
            for (int d = 0; d < EMB; ++d) dv += e[d] * uid[(size_t)j * EMB + d];
            tsum += dv;
        }
        out[b] = (sbelow + red[0] + tsum) / (float)KSEL;
    }
}

extern "C" void kernel_launch(void* const* d_in, const int* in_sizes, int n_in,
                              void* d_out, int out_size, void* d_ws, size_t ws_size,
                              hipStream_t stream) {
    const float* x     = (const float*)d_in[0];
    const float* uid   = (const float*)d_in[1];
    const float* iid_w = (const float*)d_in[2];
    const float* rp    = (const float*)d_in[3];
    float* out = (float*)d_out;

    char* ws = (char*)d_ws;
    float*    s_pre    = (float*)(ws + OFF_SPRE);
    float*    iid_emb  = (float*)(ws + OFF_IIDE);
    uint32_t* ghist    = (uint32_t*)(ws + OFF_GHIST);
    uint32_t* base16   = (uint32_t*)(ws + OFF_BASE16);
    uint32_t* prefix16 = (uint32_t*)(ws + OFF_PREFIX);
    uint32_t* m2       = (uint32_t*)(ws + OFF_M2);
    uint32_t* eq_cnt   = (uint32_t*)(ws + OFF_EQ);
    uint32_t* part     = (uint32_t*)(ws + OFF_PART);

    const size_t off_cand2 = OFF_PART + PART_BYTES;
    const bool use_part = ws_size >= off_cand2 + (size_t)128 * 8 * 4096;

    uint64_t* cand;
    int cap;
    float* sum_part;
    int g2;
    if (use_part) {
        cand = (uint64_t*)(ws + off_cand2);
        long long cap_ll = ((long long)ws_size - (long long)off_cand2) / (128LL * 8LL);
        cap = (int)(cap_ll > 16384 ? 16384 : cap_ll);
        sum_part = (float*)part;       // part dead after scan1_part; reuse as [512][128]
        g2 = G2P;
    } else {
        cand = (uint64_t*)(ws + OFF_CAND);
        long long cap_ll = ((long long)ws_size - OFF_CAND) / (128LL * 8LL);
        cap = (int)(cap_ll > 16384 ? 16384 : (cap_ll < 1 ? 1 : cap_ll));
        sum_part = (float*)(ws + OFF_GHIST);   // [256][128] overlay after scan1
        g2 = G2F;
        const int n = (OFF_CAND - OFF_GHIST) / 4;
        zero_kernel<<<(n + 255) / 256, 256, 0, stream>>>((uint32_t*)(ws + OFF_GHIST), n);
    }

    prep_kernel<<<BATCH, 64, 0, stream>>>(x, iid_w, rp, uid, s_pre, iid_emb, base16, eq_cnt);

    const int jc1 = (NU + G1 - 1) / G1;                 // 391
    if (use_part) {
        sweep1_kernel<true><<<G1, 1024, HISTW * 4, stream>>>(s_pre, uid, base16, part, jc1);
        scan1_part_kernel<<<BATCH, 256, 0, stream>>>(part, base16, prefix16, m2);
    } else {
        sweep1_kernel<false><<<G1, 1024, HISTW * 4, stream>>>(s_pre, uid, base16, ghist, jc1);
        scan1_kernel<<<1, 128, 0, stream>>>(ghist, base16, prefix16, m2);
    }

    const int jc2 = (NU + g2 - 1) / g2;
    sweep2_kernel<<<g2, 1024, 65536 + 1536, stream>>>(s_pre, iid_emb, uid,
                                                      prefix16, eq_cnt, sum_part,
                                                      cand, cap, jc2);

    final_kernel<<<BATCH, 256, 0, stream>>>(iid_emb, uid, m2, eq_cnt, sum_part,
                                            cand, cap, g2, out);
}

// Round 9
// 225.332 us; speedup vs baseline: 1.3559x; 1.1024x over previous
//
#include <hip/hip_runtime.h>
#include <hip/hip_bf16.h>
#include <stdint.h>

#define EMB    32
#define BATCH  128
#define NU     200000
#define KSEL   50000
#define XCOLS  33
#define SLOTS  32
#define G1     512          // sweep1 grid (2 blocks/CU)
#define G2P    512          // sweep2 grid, part path
#define G2F    256          // sweep2 grid, fallback path
#define HISTW  (128 * 129)  // packed u16 hist words per block
#define T1     32           // sweep1 tile rows
#define T2     64           // sweep2 tile rows

// ws layout
#define OFF_SPRE   0
#define OFF_IIDE   16384
#define OFF_GHIST  32768    // fallback: 128*256 u32 ghist; also fallback sum_part overlay
#define OFF_BASE16 163840
#define OFF_PREFIX 164352
#define OFF_M2     164864
#define OFF_EQ     165376   // 128 counters, stride 16 u32
#define OFF_CAND   173568   // fallback cand base
#define OFF_PART   173568   // part path: [512][16512] u32 = 33.82 MB; reused as sum_part after scan
#define PART_BYTES ((size_t)G1 * HISTW * 4)

// lane^1 exchange via DPP quad_perm [1,0,3,2] — VALU pipe, no LDS
__device__ __forceinline__ float xor1(float x) {
    int r = __builtin_amdgcn_update_dpp(0, __float_as_int(x), 0xB1, 0xF, 0xF, true);
    return __int_as_float(r);
}

// THE shared dot: identical FMA chain in sweep1 and sweep2 => bit-identical keys
__device__ __forceinline__ float dotrow(const float* __restrict__ c,
                                        const float* __restrict__ u) {
    float d = 0.f;
    #pragma unroll
    for (int q = 0; q < 8; ++q) {
        const float4 v = *(const float4*)(u + q * 4);
        d += c[4*q+0]*v.x + c[4*q+1]*v.y + c[4*q+2]*v.z + c[4*q+3]*v.w;
    }
    return d;
}

// ---------------- prep ----------------
__global__ void prep_kernel(const float* __restrict__ x,
                            const float* __restrict__ iid_w,
                            const float* __restrict__ rp,
                            const float* __restrict__ uid,
                            float* __restrict__ s_pre,
                            float* __restrict__ iid_emb,
                            uint32_t* __restrict__ base16,
                            uint32_t* __restrict__ eq_cnt) {
    const int b = blockIdx.x;
    const int t = threadIdx.x;          // 64 threads
    __shared__ float xr[EMB];
    if (t < EMB) xr[t] = x[b * XCOLS + 1 + t];
    if (t == 63) eq_cnt[b * 16] = 0u;
    __syncthreads();
    if (t < EMB) {
        float acc = 0.f;
        #pragma unroll
        for (int k = 0; k < EMB; ++k) acc += xr[k] * rp[t * EMB + k];
        s_pre[b * EMB + t] = acc;
    } else {
        const int d = t - EMB;
        const int iid = (int)x[b * XCOLS];
        iid_emb[b * EMB + d] = iid_w[(size_t)iid * EMB + d];
    }
    __syncthreads();
    if (t == 0) {
        float dot = 0.f;
        #pragma unroll
        for (int k = 0; k < EMB; ++k) dot += s_pre[b * EMB + k] * uid[k];
        const uint32_t bits = __float_as_uint(fabsf(dot - 4.0f));
        const uint32_t hi = bits >> 16;
        base16[b] = (hi > 128u) ? (hi - 128u) : 0u;
    }
}

// ---------------- zero scratch (fallback path only) ----------------
__global__ void zero_kernel(uint32_t* __restrict__ p, int n) {
    int i = blockIdx.x * blockDim.x + threadIdx.x;
    if (i < n) p[i] = 0u;
}

// ---------------- sweep1: LDS-tile broadcast key dot, packed-u16 hist ----------------
template <bool PART>
__global__ __launch_bounds__(1024)
void sweep1_kernel(const float* __restrict__ s_pre,
                   const float* __restrict__ uid,
                   const uint32_t* __restrict__ base16,
                   uint32_t* __restrict__ gout,
                   int jchunk) {
    extern __shared__ uint32_t smem1[];
    uint32_t* hist = smem1;                         // HISTW words = 66048 B
    float* tiles = (float*)(smem1 + HISTW);         // [2][T1*EMB] = 8192 B
    const int t  = threadIdx.x;
    const int b  = t & 127;
    const int jl = t >> 7;               // 0..7, wave-uniform
    for (int i = t; i < HISTW; i += 1024) hist[i] = 0u;
    float s[EMB];
    #pragma unroll
    for (int d = 0; d < EMB; ++d) s[d] = s_pre[b * EMB + d];
    const uint32_t base = base16[b];

    const int j0 = blockIdx.x * jchunk;
    const int jend = min(j0 + jchunk, NU);
    const int nt = (jend - j0 + T1 - 1) / T1;
    const int srow = t >> 5;             // row within tile for the 1-float stage

    {   // stage tile 0
        float v = 0.f;
        if (j0 + srow < NU) v = uid[(size_t)j0 * EMB + t];
        tiles[t] = v;
    }
    __syncthreads();

    for (int tt = 0; tt < nt; ++tt) {
        const int jt = j0 + tt * T1;
        const bool has_next = (tt + 1 < nt);
        float vnext = 0.f;
        if (has_next) {                  // issue-early
            const int jn = jt + T1;
            if (jn + srow < NU) vnext = uid[(size_t)jn * EMB + t];
        }
        const float* tp = tiles + (tt & 1) * (T1 * EMB);
        const int lim = min(T1, jend - jt);
        for (int r = jl; r < lim; r += 8) {
            const float d0 = dotrow(s, tp + r * EMB);
            const uint32_t bits0 = __float_as_uint(fabsf(d0 - 4.0f));
            int dg0 = (int)(bits0 >> 16) - (int)base;
            dg0 = dg0 < 0 ? 0 : (dg0 > 255 ? 255 : dg0);
            atomicAdd(&hist[b * 129 + (dg0 >> 1)], 1u << ((dg0 & 1) * 16));
        }
        if (has_next) {                  // write-late into other buffer
            tiles[((tt + 1) & 1) * (T1 * EMB) + t] = vnext;
        }
        __syncthreads();
    }
    if (PART) {
        uint32_t* part = gout + (size_t)blockIdx.x * HISTW;
        for (int i = t; i < HISTW; i += 1024) part[i] = hist[i];
    } else {
        for (int i = t; i < 128 * 256; i += 1024) {
            const int r = i >> 8, d = i & 255;
            const uint32_t c = (hist[r * 129 + (d >> 1)] >> ((d & 1) * 16)) & 0xFFFFu;
            if (c) atomicAdd(&gout[i], c);
        }
    }
}

// ---------------- scan1 (fallback) ----------------
__global__ void scan1_kernel(const uint32_t* __restrict__ ghist,
                             const uint32_t* __restrict__ base16,
                             uint32_t* __restrict__ prefix16,
                             uint32_t* __restrict__ m2) {
    const int b = threadIdx.x;           // 128 threads, 1 block
    uint32_t cum = 0, before = 0;
    int c1 = 255;
    for (int d = 0; d < 256; ++d) {
        const uint32_t c = ghist[b * 256 + d];
        if (cum + c >= (uint32_t)KSEL) { c1 = d; before = cum; break; }
        cum += c;
        if (d == 255) before = cum;
    }
    prefix16[b] = base16[b] + (uint32_t)c1;
    m2[b] = (uint32_t)KSEL - before;
}

// ---------------- scan1 (part path): merge packed block hists ----------
__global__ __launch_bounds__(256)
void scan1_part_kernel(const uint32_t* __restrict__ part,
                       const uint32_t* __restrict__ base16,
                       uint32_t* __restrict__ prefix16,
                       uint32_t* __restrict__ m2) {
    const int row = blockIdx.x;          // 128 blocks
    const int t = threadIdx.x;           // 256 threads = digits
    __shared__ uint32_t h[256];
    const int sh = (t & 1) * 16;
    const uint32_t* p = part + (size_t)row * 129 + (t >> 1);
    uint32_t a0 = 0, a1 = 0, a2 = 0, a3 = 0;
    for (int g = 0; g < G1; g += 4) {
        a0 += (p[(size_t)(g + 0) * HISTW] >> sh) & 0xFFFFu;
        a1 += (p[(size_t)(g + 1) * HISTW] >> sh) & 0xFFFFu;
        a2 += (p[(size_t)(g + 2) * HISTW] >> sh) & 0xFFFFu;
        a3 += (p[(size_t)(g + 3) * HISTW] >> sh) & 0xFFFFu;
    }
    h[t] = a0 + a1 + a2 + a3;
    __syncthreads();
    if (t == 0) {
        uint32_t cum = 0, before = 0; int c1 = 255;
        for (int d = 0; d < 256; ++d) {
            const uint32_t c = h[d];
            if (cum + c >= (uint32_t)KSEL) { c1 = d; before = cum; break; }
            cum += c;
            if (d == 255) before = cum;
        }
        prefix16[row] = base16[row] + (uint32_t)c1;
        m2[row] = (uint32_t)KSEL - before;
    }
}

// ---------------- sweep2: role-split + LDS broadcast tiles ----------
__global__ __launch_bounds__(1024)
void sweep2_kernel(const float* __restrict__ s_pre,
                   const float* __restrict__ iid_emb,
                   const float* __restrict__ uid,
                   const uint32_t* __restrict__ prefix16,
                   uint32_t* __restrict__ eq_cnt,
                   float* __restrict__ sum_part,
                   uint64_t* __restrict__ cand,
                   int cap, int jchunk) {
    extern __shared__ char smem2[];
    uint64_t* lcand  = (uint64_t*)smem2;                   // 128*32*8 = 32768
    float*    tiles  = (float*)(smem2 + 32768);            // [2][T2*EMB] = 16384
    uint32_t* lcnt   = (uint32_t*)(smem2 + 49152);         // 512
    uint32_t* lbase  = (uint32_t*)(smem2 + 49664);         // 512
    float*    sums_b = (float*)(smem2 + 50176);            // 512
    const int t   = threadIdx.x;
    const int par = t & 1;               // 0: key (s_pre), 1: val (iid_emb)
    const int pr  = t >> 1;              // 0..511
    const int b   = pr & 127;
    const int jl  = pr >> 7;             // 0..3, wave-uniform
    if (t < 128) { lcnt[t] = 0u; sums_b[t] = 0.f; }
    float c[EMB];
    {
        const float4* cp4 = (const float4*)((par ? iid_emb : s_pre) + b * EMB);
        #pragma unroll
        for (int q = 0; q < 8; ++q) {
            float4 v = cp4[q];
            c[4*q+0] = v.x; c[4*q+1] = v.y; c[4*q+2] = v.z; c[4*q+3] = v.w;
        }
    }
    const uint32_t pfx = prefix16[b];

    const int j0 = blockIdx.x * jchunk;
    const int jend = min(j0 + jchunk, NU);
    const int nt = (jend - j0 + T2 - 1) / T2;
    const int srow = t >> 4;             // row within tile for the float2 stage

    {   // stage tile 0
        float2 v = make_float2(0.f, 0.f);
        if (j0 + srow < NU) v = *(const float2*)(uid + (size_t)j0 * EMB + t * 2);
        *(float2*)(tiles + t * 2) = v;
    }
    __syncthreads();

    float local = 0.f;
    for (int tt = 0; tt < nt; ++tt) {
        const int jt = j0 + tt * T2;
        const bool has_next = (tt + 1 < nt);
        float2 vnext = make_float2(0.f, 0.f);
        if (has_next) {                  // issue-early
            const int jn = jt + T2;
            if (jn + srow < NU) vnext = *(const float2*)(uid + (size_t)jn * EMB + t * 2);
        }
        const float* tp = tiles + (tt & 1) * (T2 * EMB);
        const int lim = min(T2, jend - jt);
        for (int r = jl; r < lim; r += 4) {
            const float a0 = dotrow(c, tp + r * EMB);
            const float p0 = xor1(a0);   // even lane receives partner's val-dot
            if (par == 0) {
                const uint32_t bits0 = __float_as_uint(fabsf(a0 - 4.0f));
                const uint32_t hi0 = bits0 >> 16;
                local += (hi0 < pfx) ? p0 : 0.f;
                if (hi0 == pfx) {
                    const uint32_t pos = atomicAdd(&lcnt[b], 1u);
                    const uint64_t pk = ((uint64_t)bits0 << 32) | (uint32_t)(jt + r);
                    if (pos < (uint32_t)SLOTS) lcand[b * SLOTS + pos] = pk;
                    else {
                        const uint32_t g = atomicAdd(&eq_cnt[b * 16], 1u);
                        if (g < (uint32_t)cap) cand[(size_t)b * cap + g] = pk;
                    }
                }
            }
        }
        if (has_next) {                  // write-late into other buffer
            *(float2*)(tiles + ((tt + 1) & 1) * (T2 * EMB) + t * 2) = vnext;
        }
        __syncthreads();
    }
    if (par == 0 && local != 0.f) atomicAdd(&sums_b[b], local);
    __syncthreads();
    if (t < 128) {
        sum_part[(size_t)blockIdx.x * 128 + t] = sums_b[t];
        const uint32_t n = min(lcnt[t], (uint32_t)SLOTS);
        lbase[t] = atomicAdd(&eq_cnt[t * 16], n);
    }
    __syncthreads();
    for (int i = t; i < 128 * SLOTS; i += 1024) {
        const int bb = i >> 5;             // SLOTS == 32
        const int sl = i & 31;
        if (sl < (int)min(lcnt[bb], (uint32_t)SLOTS)) {
            const uint32_t p = lbase[bb] + (uint32_t)sl;
            if (p < (uint32_t)cap) cand[(size_t)bb * cap + p] = lcand[i];
        }
    }
}

// ---------------- finalize ----------------
__global__ __launch_bounds__(256)
void final_kernel(const float* __restrict__ iid_emb,
                  const float* __restrict__ uid,
                  const uint32_t* __restrict__ m2_,
                  const uint32_t* __restrict__ eq_cnt,
                  const float* __restrict__ sum_part,
                  const uint64_t* __restrict__ cand,
                  int cap, int g2, float* __restrict__ out) {
    const int b = blockIdx.x;
    const int t = threadIdx.x;           // 256 threads
    __shared__ float red[256];
    __shared__ uint32_t hist[256];
    __shared__ float e[EMB];
    __shared__ uint32_t tie[128];
    __shared__ uint32_t tiecnt, sc2, sm3, sc3, sm4;
    __shared__ float sbelow;
    if (t < EMB) e[t] = iid_emb[b * EMB + t];
    if (t == 0) tiecnt = 0u;
    hist[t] = 0u;
    {
        float acc = 0.f;
        for (int g = t; g < g2; g += 256) acc += sum_part[(size_t)g * 128 + b];
        red[t] = acc;
    }
    __syncthreads();
    for (int s = 128; s > 0; s >>= 1) { if (t < s) red[t] += red[t + s]; __syncthreads(); }
    if (t == 0) sbelow = red[0];
    __syncthreads();

    const uint32_t ec = eq_cnt[b * 16];
    const int cnt = (int)(ec < (uint32_t)cap ? ec : (uint32_t)cap);
    const uint64_t* cb = cand + (size_t)b * cap;

    for (int i = t; i < cnt; i += 256) {
        const uint32_t low16 = (uint32_t)(cb[i] >> 32) & 0xFFFFu;
        atomicAdd(&hist[low16 >> 8], 1u);
    }
    __syncthreads();
    if (t == 0) {
        const uint32_t m2v = m2_[b];
        uint32_t cum = 0, before = 0; int c2 = 255;
        for (int d = 0; d < 256; ++d) {
            const uint32_t c = hist[d];
            if (cum + c >= m2v) { c2 = d; before = cum; break; }
            cum += c;
        }
        sc2 = (uint32_t)c2; sm3 = m2v - before;
    }
    __syncthreads();
    const uint32_t c2 = sc2;
    hist[t] = 0u;
    __syncthreads();

    for (int i = t; i < cnt; i += 256) {
        const uint32_t low16 = (uint32_t)(cb[i] >> 32) & 0xFFFFu;
        if ((low16 >> 8) == c2) atomicAdd(&hist[low16 & 255u], 1u);
    }
    __syncthreads();
    if (t == 0) {
        const uint32_t m3 = sm3;
        uint32_t cum = 0, before = 0; int c3 = 255;
        for (int d = 0; d < 256; ++d) {
            const uint32_t c = hist[d];
            if (cum + c >= m3) { c3 = d; before = cum; break; }
            cum += c;
        }
        sc3 = (uint32_t)c3; sm4 = m3 - before;
    }
    __syncthreads();
    const uint32_t T16 = (c2 << 8) | sc3;

    float local = 0.f;
    for (int i = t; i < cnt; i += 256) {
        const uint64_t cv = cb[i];
        const uint32_t low16 = (uint32_t)(cv >> 32) & 0xFFFFu;
        if (low16 < T16) {
            const uint32_t j = (uint32_t)cv;
            const float4* u4 = (const float4*)(uid + (size_t)j * EMB);
            float dv = 0.f;
            #pragma unroll
            for (int q = 0; q < 8; ++q) {
                float4 u = u4[q];
                dv += e[4*q+0]*u.x + e[4*q+1]*u.y + e[4*q+2]*u.z + e[4*q+3]*u.w;
            }
            local += dv;
        } else if (low16 == T16) {
            const uint32_t pos = atomicAdd(&tiecnt, 1u);
            if (pos < 128u) tie[pos] = (uint32_t)cv;
        }
    }
    red[t] = local;
    __syncthreads();
    for (int s = 128; s > 0; s >>= 1) { if (t < s) red[t] += red[t + s]; __syncthreads(); }
    if (t == 0) {
        int tc = (int)(tiecnt < 128u ? tiecnt : 128u);
        for (int i = 1; i < tc; ++i) {
            const uint32_t v = tie[i]; int k = i - 1;
            while (k >= 0 && tie[k] > v) { tie[k+1] = tie[k]; --k; }
            tie[k+1] = v;
        }
        const int m4 = (int)sm4;
        float tsum = 0.f;
        for (int i = 0; i < m4 && i < tc; ++i) {
            const uint32_t j = tie[i];
            float dv = 0.f;
            for (int d = 0; d < EMB; ++d) dv += e[d] * uid[(size_t)j * EMB + d];
            tsum += dv;
        }
        out[b] = (sbelow + red[0] + tsum) / (float)KSEL;
    }
}

extern "C" void kernel_launch(void* const* d_in, const int* in_sizes, int n_in,
                              void* d_out, int out_size, void* d_ws, size_t ws_size,
                              hipStream_t stream) {
    const float* x     = (const float*)d_in[0];
    const float* uid   = (const float*)d_in[1];
    const float* iid_w = (const float*)d_in[2];
    const float* rp    = (const float*)d_in[3];
    float* out = (float*)d_out;

    char* ws = (char*)d_ws;
    float*    s_pre    = (float*)(ws + OFF_SPRE);
    float*    iid_emb  = (float*)(ws + OFF_IIDE);
    uint32_t* ghist    = (uint32_t*)(ws + OFF_GHIST);
    uint32_t* base16   = (uint32_t*)(ws + OFF_BASE16);
    uint32_t* prefix16 = (uint32_t*)(ws + OFF_PREFIX);
    uint32_t* m2       = (uint32_t*)(ws + OFF_M2);
    uint32_t* eq_cnt   = (uint32_t*)(ws + OFF_EQ);
    uint32_t* part     = (uint32_t*)(ws + OFF_PART);

    const size_t off_cand2 = OFF_PART + PART_BYTES;
    const bool use_part = ws_size >= off_cand2 + (size_t)128 * 8 * 4096;

    uint64_t* cand;
    int cap;
    float* sum_part;
    int g2;
    if (use_part) {
        cand = (uint64_t*)(ws + off_cand2);
        long long cap_ll = ((long long)ws_size - (long long)off_cand2) / (128LL * 8LL);
        cap = (int)(cap_ll > 16384 ? 16384 : cap_ll);
        sum_part = (float*)part;       // part dead after scan1_part; reuse as [512][128]
        g2 = G2P;
    } else {
        cand = (uint64_t*)(ws + OFF_CAND);
        long long cap_ll = ((long long)ws_size - OFF_CAND) / (128LL * 8LL);
        cap = (int)(cap_ll > 16384 ? 16384 : (cap_ll < 1 ? 1 : cap_ll));
        sum_part = (float*)(ws + OFF_GHIST);   // [256][128] overlay after scan1
        g2 = G2F;
        const int n = (OFF_CAND - OFF_GHIST) / 4;
        zero_kernel<<<(n + 255) / 256, 256, 0, stream>>>((uint32_t*)(ws + OFF_GHIST), n);
    }

    prep_kernel<<<BATCH, 64, 0, stream>>>(x, iid_w, rp, uid, s_pre, iid_emb, base16, eq_cnt);

    const int jc1 = (NU + G1 - 1) / G1;                 // 391
    const size_t lds1 = HISTW * 4 + 2 * T1 * EMB * 4;   // 74240
    if (use_part) {
        sweep1_kernel<true><<<G1, 1024, lds1, stream>>>(s_pre, uid, base16, part, jc1);
        scan1_part_kernel<<<BATCH, 256, 0, stream>>>(part, base16, prefix16, m2);
    } else {
        sweep1_kernel<false><<<G1, 1024, lds1, stream>>>(s_pre, uid, base16, ghist, jc1);
        scan1_kernel<<<1, 128, 0, stream>>>(ghist, base16, prefix16, m2);
    }

    const int jc2 = (NU + g2 - 1) / g2;
    const size_t lds2 = 32768 + 16384 + 1536;           // 50688
    sweep2_kernel<<<g2, 1024, lds2, stream>>>(s_pre, iid_emb, uid,
                                              prefix16, eq_cnt, sum_part,
                                              cand, cap, jc2);

    final_kernel<<<BATCH, 256, 0, stream>>>(iid_emb, uid, m2, eq_cnt, sum_part,
                                            cand, cap, g2, out);
}